// Round 5
// baseline (2002.607 us; speedup 1.0000x reference)
//
#include <hip/hip_runtime.h>
#include <hip/hip_fp16.h>
#include <math.h>

#define R2 2500.0f
#define EPSF 1e-8f

constexpr int H  = 256;    // feature dim
constexpr int HH = 128;    // hidden dim
constexpr int NB_COL = 128;              // col-block (slice) size in nodes
constexpr int NB_ROW = 64;               // rows per workgroup
constexpr int NN = 16384;
constexpr int NPASS = NN / NB_COL;       // 128
constexpr int NWG   = NN / NB_ROW;       // 256
constexpr int NBUCKET = NWG * NPASS;     // 32768

// ---------------- K1: degree count ----------------
__global__ void k_degree(const int* __restrict__ row, int* __restrict__ deg, int E) {
    int e = blockIdx.x * blockDim.x + threadIdx.x;
    if (e < E) atomicAdd(&deg[row[e]], 1);
}

// ---------------- K2: bucket count ----------------
__global__ void k_bcount(const int* __restrict__ row, const int* __restrict__ col,
                         int* __restrict__ bcnt, int E) {
    int e = blockIdx.x * blockDim.x + threadIdx.x;
    if (e < E) {
        int b = ((row[e] >> 6) << 7) | (col[e] >> 7);
        atomicAdd(&bcnt[b], 1);
    }
}

// ---------------- K3: exclusive scan over 32768 buckets (1 block) ----------------
__global__ void k_bscan(const int* __restrict__ bcnt, int* __restrict__ bptr, int total) {
    __shared__ int s[1024];
    int t = threadIdx.x;
    int per = total >> 10;           // 32
    int base = t * per;
    int vals[32];
    int local = 0;
    for (int k = 0; k < per; k++) { vals[k] = bcnt[base + k]; local += vals[k]; }
    s[t] = local;
    __syncthreads();
    for (int off = 1; off < 1024; off <<= 1) {
        int v = s[t];
        int add = (t >= off) ? s[t - off] : 0;
        __syncthreads();
        s[t] = v + add;
        __syncthreads();
    }
    int excl = (t > 0) ? s[t - 1] : 0;
    for (int k = 0; k < per; k++) { bptr[base + k] = excl; excl += vals[k]; }
    if (t == 1023) bptr[total] = excl;
}

// ---------------- K4: bucket fill (packed u16: row_local<<7 | col_local) ------
__global__ void k_bfill(const int* __restrict__ row, const int* __restrict__ col,
                        const int* __restrict__ bptr, int* __restrict__ bfill,
                        unsigned short* __restrict__ bedge, int E) {
    int e = blockIdx.x * blockDim.x + threadIdx.x;
    if (e < E) {
        int r = row[e], c = col[e];
        int b = ((r >> 6) << 7) | (c >> 7);
        int p = bptr[b] + atomicAdd(&bfill[b], 1);
        bedge[p] = (unsigned short)(((r & 63) << 7) | (c & 127));
    }
}

// ---------------- K5: x -> fp16 copy ----------------
__global__ void k_half(const float* __restrict__ x, unsigned short* __restrict__ xh,
                       int total4) {
    int t = blockIdx.x * blockDim.x + threadIdx.x;
    if (t < total4) {
        float4 v = ((const float4*)x)[t];
        __half2 a = __floats2half2_rn(v.x, v.y);
        __half2 b = __floats2half2_rn(v.z, v.w);
        uint2 r;
        r.x = __builtin_bit_cast(unsigned int, a);
        r.y = __builtin_bit_cast(unsigned int, b);
        ((uint2*)xh)[t] = r;
    }
}

// ---------------- K6: spatial density (pairwise count) ----------------
__global__ void k_density(const float* __restrict__ coords, int* __restrict__ dens,
                          int N, int jPer) {
    __shared__ float sx[256], sy[256], sq[256];
    int i = blockIdx.x * 256 + threadIdx.x;
    const float2* c2 = (const float2*)coords;
    float2 ci = c2[i];
    float sqi = ci.x * ci.x + ci.y * ci.y;
    int j0 = blockIdx.y * jPer;
    int cnt = 0;
    for (int jt = j0; jt < j0 + jPer; jt += 256) {
        float2 cj = c2[jt + threadIdx.x];
        sx[threadIdx.x] = cj.x;
        sy[threadIdx.x] = cj.y;
        sq[threadIdx.x] = cj.x * cj.x + cj.y * cj.y;
        __syncthreads();
#pragma unroll 8
        for (int k = 0; k < 256; k++) {
            float dot = ci.x * sx[k] + ci.y * sy[k];
            float d2 = (sqi + sq[k]) - 2.0f * dot;
            cnt += (d2 <= R2) ? 1 : 0;
        }
        __syncthreads();
    }
    atomicAdd(&dens[i], cnt);
}

// ---------------- K7: fvar via bucketed LDS-staged SpMM ----------------
// wg = 64 rows; 128 passes over 128-node col slices. Staging is coalesced
// global->reg->LDS (reg-prefetched one pass ahead); per-edge work is pure LDS:
// broadcast u16, ds_read_b64 slice row, 4x ds_add_f32 into fp32 accumulators.
// No random global access anywhere.
__global__ void __launch_bounds__(512) k_fvarZ(
    const float* __restrict__ x, const unsigned short* __restrict__ xh,
    const int* __restrict__ bptr, const unsigned short* __restrict__ bedge,
    const int* __restrict__ deg, const int* __restrict__ dens,
    float* __restrict__ fvar, int* __restrict__ scal) {
    extern __shared__ char smem[];
    uint2* slice = (uint2*)smem;                          // [NB_COL*64]  64KB fp16
    float* acc   = (float*)(smem + NB_COL * 64 * 8);      // [NB_ROW*256] 64KB fp32
    int t = threadIdx.x;
    int wave = t >> 6, lane = t & 63;
    int wg = blockIdx.x;

    for (int k = t; k < NB_ROW * 256; k += 512) acc[k] = 0.f;

    const uint4* xh4 = (const uint4*)xh;   // one x-row = 32 uint4
    uint4 pf[8];
    {
        const uint4* src = xh4;            // pass 0 slice: nodes [0,128)
#pragma unroll
        for (int k = 0; k < 8; k++) pf[k] = src[t + k * 512];
    }
    const int bbase = wg * NPASS;
    __syncthreads();   // acc zero visible

    for (int p = 0; p < NPASS; p++) {
        uint4* sl4 = (uint4*)slice;
#pragma unroll
        for (int k = 0; k < 8; k++) sl4[t + k * 512] = pf[k];
        if (p + 1 < NPASS) {
            const uint4* src = xh4 + (size_t)(p + 1) * (NB_COL * 32);
#pragma unroll
            for (int k = 0; k < 8; k++) pf[k] = src[t + k * 512];
        }
        __syncthreads();   // slice ready
        int s = bptr[bbase + p], e = bptr[bbase + p + 1];
        for (int q = s + wave; q < e; q += 8) {
            unsigned short pk = bedge[q];
            int r  = pk >> 7;
            int cl = pk & 127;
            uint2 hv = slice[cl * 64 + lane];
            __half2 h0 = __builtin_bit_cast(__half2, hv.x);
            __half2 h1 = __builtin_bit_cast(__half2, hv.y);
            float2 f0 = __half22float2(h0);
            float2 f1 = __half22float2(h1);
            float* ar = acc + r * 256 + lane * 4;
            atomicAdd(ar + 0, f0.x);
            atomicAdd(ar + 1, f0.y);
            atomicAdd(ar + 2, f1.x);
            atomicAdd(ar + 3, f1.y);
        }
        __syncthreads();   // edges done before slice overwrite
    }

    // epilogue: wave owns rows [wave*8, wave*8+8)
    for (int rr = 0; rr < 8; rr++) {
        int r = wave * 8 + rr;
        int i = wg * NB_ROW + r;
        int dg = deg[i];
        float cnt = fmaxf((float)dg, 1.0f);
        float4 xi = ((const float4*)x)[(size_t)i * 64 + lane];
        float4 av = *(const float4*)(acc + r * 256 + lane * 4);
        float dx = xi.x - av.x / cnt;
        float dy = xi.y - av.y / cnt;
        float dz = xi.z - av.z / cnt;
        float dw = xi.w - av.w / cnt;
        float ss = dx * dx + dy * dy + dz * dz + dw * dw;
#pragma unroll
        for (int off = 32; off > 0; off >>= 1) ss += __shfl_xor(ss, off, 64);
        if (lane == 0) {
            float fv = sqrtf(ss);
            fvar[i] = fv;
            atomicMax(&scal[0], dg);
            atomicMax(&scal[1], dens[i]);
            atomicMax(&scal[2], __float_as_int(fv));
        }
    }
}

// ---------------- K8: tiny MLP ----------------
__global__ void __launch_bounds__(256) k_mlp(
    const float* __restrict__ w1, const float* __restrict__ b1,
    const float* __restrict__ w2, const float* __restrict__ b2,
    const int* __restrict__ deg, const int* __restrict__ dens,
    const float* __restrict__ fvar, const int* __restrict__ scal,
    float* __restrict__ out, int N) {
    __shared__ float sh_h[HH];
    int j = threadIdx.x;
    float wv[HH];
#pragma unroll
    for (int l = 0; l < HH; l++) wv[l] = w2[l * H + j];
    float bj = b2[j];
    float maxdeg  = (float)scal[0] + EPSF;
    float maxdens = (float)(scal[1] - 1) + EPSF;
    float maxfv   = __int_as_float(scal[2]) + EPSF;
    float w1a = 0.f, w1b = 0.f, w1c = 0.f, b1j = 0.f;
    if (j < HH) { w1a = w1[j]; w1b = w1[HH + j]; w1c = w1[2 * HH + j]; b1j = b1[j]; }
    for (int i = blockIdx.x; i < N; i += gridDim.x) {
        float f0 = (float)deg[i] / maxdeg;
        float f1 = (float)(dens[i] - 1) / maxdens;
        float f2 = fvar[i] / maxfv;
        if (j < HH) {
            float h = f0 * w1a + f1 * w1b + f2 * w1c + b1j;
            sh_h[j] = fmaxf(h, 0.0f);
        }
        __syncthreads();
        float acc = bj;
#pragma unroll
        for (int l = 0; l < HH; l++) acc = fmaf(sh_h[l], wv[l], acc);
        out[(size_t)i * H + j] = acc;
        __syncthreads();
    }
}

extern "C" void kernel_launch(void* const* d_in, const int* in_sizes, int n_in,
                              void* d_out, int out_size, void* d_ws, size_t ws_size,
                              hipStream_t stream) {
    const float* x      = (const float*)d_in[0];
    const int*   ei     = (const int*)d_in[1];
    const float* coords = (const float*)d_in[2];
    const float* w1     = (const float*)d_in[3];
    const float* b1     = (const float*)d_in[4];
    const float* w2     = (const float*)d_in[5];
    const float* b2     = (const float*)d_in[6];
    float* out = (float*)d_out;

    const int N = in_sizes[2] / 2;   // 16384
    const int E = in_sizes[1] / 2;   // 524288
    const int* row = ei;
    const int* col = ei + E;

    // workspace layout (int32 elements)
    int* ws       = (int*)d_ws;
    int* deg_cnt  = ws;                         // [N]      zeroed
    int* dens_cnt = ws + N;                     // [N]      zeroed
    int* scal     = ws + 2 * N;                 // [4]      zeroed
    int* bcnt     = ws + 2 * N + 4;             // [32768]  zeroed
    int* bfill    = bcnt + NBUCKET;             // [32768]  zeroed
    int* bptr     = bfill + NBUCKET;            // [32772] (padded)
    float* fvarp  = (float*)(bptr + NBUCKET + 4);              // [N]
    unsigned short* bedge = (unsigned short*)(fvarp + N);      // [E] u16
    unsigned short* xh    = bedge + E;                         // [N*H] u16 (16B-aligned)

    hipMemsetAsync(ws, 0, (size_t)(2 * N + 4 + 2 * NBUCKET) * sizeof(int), stream);

    int eb = (E + 255) / 256;
    k_degree<<<eb, 256, 0, stream>>>(row, deg_cnt, E);
    k_bcount<<<eb, 256, 0, stream>>>(row, col, bcnt, E);
    k_bscan<<<1, 1024, 0, stream>>>(bcnt, bptr, NBUCKET);
    k_bfill<<<eb, 256, 0, stream>>>(row, col, bptr, bfill, bedge, E);

    int t4 = N * (H / 4);
    k_half<<<(t4 + 255) / 256, 256, 0, stream>>>(x, xh, t4);

    const int NSLICE = 8;
    k_density<<<dim3(N / 256, NSLICE), 256, 0, stream>>>(coords, dens_cnt, N, N / NSLICE);

    static bool attr_set = false;
    hipFuncSetAttribute((const void*)k_fvarZ,
                        hipFuncAttributeMaxDynamicSharedMemorySize, 131072);
    (void)attr_set;
    k_fvarZ<<<NWG, 512, 131072, stream>>>(x, xh, bptr, bedge, deg_cnt, dens_cnt,
                                          fvarp, scal);

    k_mlp<<<1024, 256, 0, stream>>>(w1, b1, w2, b2, deg_cnt, dens_cnt, fvarp, scal,
                                    out, N);
}

// Round 6
// 1655.890 us; speedup vs baseline: 1.2094x; 1.2094x over previous
//
#include <hip/hip_runtime.h>
#include <hip/hip_fp16.h>
#include <math.h>

#define R2 2500.0f
#define EPSF 1e-8f

constexpr int H  = 256;    // feature dim
constexpr int HH = 128;    // hidden dim
constexpr int NN = 16384;
constexpr int EE = 524288;

// fvar SpMM geometry
constexpr int SLICE_COLS = 256;               // cols per staged slice (128KB fp16)
constexpr int NPASS = NN / SLICE_COLS;        // 64
constexpr int ROWS_WG = 64;                   // 8 waves x 8 rows
constexpr int NWG = NN / ROWS_WG;             // 256
constexpr int NRG = NN / 8;                   // 2048 rowgroups
constexpr int NB2 = NRG * NPASS;              // 131072 buckets
constexpr int MAXE_W = 512;                   // max edges per rowgroup (Poisson(256), 16 sigma)

// ---------------- K1: degree + bucket count (merged) ----------------
__global__ void k_prep(const int* __restrict__ row, const int* __restrict__ col,
                       int* __restrict__ deg, int* __restrict__ bcnt, int E) {
    int e = blockIdx.x * blockDim.x + threadIdx.x;
    if (e < E) {
        int r = row[e], c = col[e];
        atomicAdd(&deg[r], 1);
        atomicAdd(&bcnt[(r >> 3) * NPASS + (c >> 8)], 1);
    }
}

// ---------------- K2: exclusive scan over 131072 buckets (1 block) -----------
// per-thread 128 elements: sum pass (no storage), LDS scan, re-read pass.
__global__ void k_bscan(const int* __restrict__ bcnt, int* __restrict__ bptr, int total) {
    __shared__ int s[1024];
    int t = threadIdx.x;
    int per = total >> 10;           // 128
    int base = t * per;
    int local = 0;
    for (int k = 0; k < per; k++) local += bcnt[base + k];
    s[t] = local;
    __syncthreads();
    for (int off = 1; off < 1024; off <<= 1) {
        int v = s[t];
        int add = (t >= off) ? s[t - off] : 0;
        __syncthreads();
        s[t] = v + add;
        __syncthreads();
    }
    int excl = (t > 0) ? s[t - 1] : 0;
    for (int k = 0; k < per; k++) {
        int v = bcnt[base + k];
        bptr[base + k] = excl;
        excl += v;
    }
    if (t == 1023) bptr[total] = excl;
}

// ---------------- K3: bucket fill (u32: row_local<<14 | col) ----------------
__global__ void k_bfill(const int* __restrict__ row, const int* __restrict__ col,
                        const int* __restrict__ bptr, int* __restrict__ bfill,
                        unsigned int* __restrict__ bedge, int E) {
    int e = blockIdx.x * blockDim.x + threadIdx.x;
    if (e < E) {
        int r = row[e], c = col[e];
        int b = (r >> 3) * NPASS + (c >> 8);
        int p = bptr[b] + atomicAdd(&bfill[b], 1);
        bedge[p] = ((unsigned int)(r & 7) << 14) | (unsigned int)c;
    }
}

// ---------------- K4: x -> fp16 copy ----------------
__global__ void k_half(const float* __restrict__ x, unsigned short* __restrict__ xh,
                       int total4) {
    int t = blockIdx.x * blockDim.x + threadIdx.x;
    if (t < total4) {
        float4 v = ((const float4*)x)[t];
        __half2 a = __floats2half2_rn(v.x, v.y);
        __half2 b = __floats2half2_rn(v.z, v.w);
        uint2 r;
        r.x = __builtin_bit_cast(unsigned int, a);
        r.y = __builtin_bit_cast(unsigned int, b);
        ((uint2*)xh)[t] = r;
    }
}

// ---------------- K5: spatial density (pairwise count) ----------------
__global__ void k_density(const float* __restrict__ coords, int* __restrict__ dens,
                          int N, int jPer) {
    __shared__ float sx[256], sy[256], sq[256];
    int i = blockIdx.x * 256 + threadIdx.x;
    const float2* c2 = (const float2*)coords;
    float2 ci = c2[i];
    float sqi = ci.x * ci.x + ci.y * ci.y;
    int j0 = blockIdx.y * jPer;
    int cnt = 0;
    for (int jt = j0; jt < j0 + jPer; jt += 256) {
        float2 cj = c2[jt + threadIdx.x];
        sx[threadIdx.x] = cj.x;
        sy[threadIdx.x] = cj.y;
        sq[threadIdx.x] = cj.x * cj.x + cj.y * cj.y;
        __syncthreads();
#pragma unroll 8
        for (int k = 0; k < 256; k++) {
            float dot = ci.x * sx[k] + ci.y * sy[k];
            float d2 = (sqi + sq[k]) - 2.0f * dot;
            cnt += (d2 <= R2) ? 1 : 0;
        }
        __syncthreads();
    }
    atomicAdd(&dens[i], cnt);
}

// ---------------- K6: fvar streaming SpMM ----------------
// Wave owns 8 rows; acc = 8 x float4 in VGPRs (no atomics). 64 passes stage
// 256-col fp16 X slices into LDS (coalesced, reg-prefetched one pass ahead).
// Wave's edges (bucket-sorted by pass) staged once into LDS; per edge:
// broadcast u32 read + ds_read_b64 slice row + uniform switch accumulate.
__global__ void __launch_bounds__(512) k_fvarS(
    const float* __restrict__ x, const unsigned short* __restrict__ xh,
    const int* __restrict__ bptr, const unsigned int* __restrict__ bedge,
    const int* __restrict__ deg, const int* __restrict__ dens,
    float* __restrict__ fvar, int* __restrict__ scal) {
    extern __shared__ char smem[];
    uint2* slice = (uint2*)smem;                                   // 256 cols * 512B = 128KB
    unsigned int* ledges = (unsigned int*)(smem + SLICE_COLS * 512); // 8 waves * 512 * 4B = 16KB
    int t = threadIdx.x;
    int wave = t >> 6, lane = t & 63;
    int rg = blockIdx.x * 8 + wave;            // rowgroup: rows rg*8 .. rg*8+7

    int s = bptr[rg * NPASS];
    int cnt = bptr[rg * NPASS + NPASS] - s;
    if (cnt > MAXE_W) cnt = MAXE_W;
    for (int k = lane; k < cnt; k += 64) ledges[wave * MAXE_W + k] = bedge[s + k];

    const uint4* xh4 = (const uint4*)xh;       // one pass slice = 8192 uint4
    uint4 pf[16];
#pragma unroll
    for (int k = 0; k < 16; k++) pf[k] = xh4[t + k * 512];

    float4 a0 = {0,0,0,0}, a1 = {0,0,0,0}, a2 = {0,0,0,0}, a3 = {0,0,0,0};
    float4 a4 = {0,0,0,0}, a5 = {0,0,0,0}, a6 = {0,0,0,0}, a7 = {0,0,0,0};
    int j = 0;
    __syncthreads();   // ledges visible

    for (int p = 0; p < NPASS; p++) {
        uint4* sl4 = (uint4*)slice;
#pragma unroll
        for (int k = 0; k < 16; k++) sl4[t + k * 512] = pf[k];
        if (p + 1 < NPASS) {
            const uint4* src = xh4 + (size_t)(p + 1) * 8192;
#pragma unroll
            for (int k = 0; k < 16; k++) pf[k] = src[t + k * 512];
        }
        __syncthreads();   // slice ready
        while (j < cnt) {
            unsigned int pk = ledges[wave * MAXE_W + j];   // broadcast (uniform)
            if (((pk >> 8) & 63u) != (unsigned int)p) break;
            int cl = pk & 255;
            uint2 hv = slice[cl * 64 + lane];
            __half2 h0 = __builtin_bit_cast(__half2, hv.x);
            __half2 h1 = __builtin_bit_cast(__half2, hv.y);
            float2 f0 = __half22float2(h0);
            float2 f1 = __half22float2(h1);
            switch (pk >> 14) {    // wave-uniform branch
                case 0: a0.x += f0.x; a0.y += f0.y; a0.z += f1.x; a0.w += f1.y; break;
                case 1: a1.x += f0.x; a1.y += f0.y; a1.z += f1.x; a1.w += f1.y; break;
                case 2: a2.x += f0.x; a2.y += f0.y; a2.z += f1.x; a2.w += f1.y; break;
                case 3: a3.x += f0.x; a3.y += f0.y; a3.z += f1.x; a3.w += f1.y; break;
                case 4: a4.x += f0.x; a4.y += f0.y; a4.z += f1.x; a4.w += f1.y; break;
                case 5: a5.x += f0.x; a5.y += f0.y; a5.z += f1.x; a5.w += f1.y; break;
                case 6: a6.x += f0.x; a6.y += f0.y; a6.z += f1.x; a6.w += f1.y; break;
                default: a7.x += f0.x; a7.y += f0.y; a7.z += f1.x; a7.w += f1.y; break;
            }
            j++;
        }
        __syncthreads();   // edges done before slice overwrite
    }

    float4 accs[8] = {a0, a1, a2, a3, a4, a5, a6, a7};
#pragma unroll
    for (int n = 0; n < 8; n++) {
        int i = rg * 8 + n;
        int dg = deg[i];
        float cntf = fmaxf((float)dg, 1.0f);
        float4 xi = ((const float4*)x)[(size_t)i * 64 + lane];
        float dx = xi.x - accs[n].x / cntf;
        float dy = xi.y - accs[n].y / cntf;
        float dz = xi.z - accs[n].z / cntf;
        float dw = xi.w - accs[n].w / cntf;
        float ss = dx * dx + dy * dy + dz * dz + dw * dw;
#pragma unroll
        for (int off = 32; off > 0; off >>= 1) ss += __shfl_xor(ss, off, 64);
        if (lane == 0) {
            float fv = sqrtf(ss);
            fvar[i] = fv;
            atomicMax(&scal[0], dg);
            atomicMax(&scal[1], dens[i]);
            atomicMax(&scal[2], __float_as_int(fv));
        }
    }
}

// ---------------- K7: tiny MLP ----------------
__global__ void __launch_bounds__(256) k_mlp(
    const float* __restrict__ w1, const float* __restrict__ b1,
    const float* __restrict__ w2, const float* __restrict__ b2,
    const int* __restrict__ deg, const int* __restrict__ dens,
    const float* __restrict__ fvar, const int* __restrict__ scal,
    float* __restrict__ out, int N) {
    __shared__ float sh_h[HH];
    int j = threadIdx.x;
    float wv[HH];
#pragma unroll
    for (int l = 0; l < HH; l++) wv[l] = w2[l * H + j];
    float bj = b2[j];
    float maxdeg  = (float)scal[0] + EPSF;
    float maxdens = (float)(scal[1] - 1) + EPSF;
    float maxfv   = __int_as_float(scal[2]) + EPSF;
    float w1a = 0.f, w1b = 0.f, w1c = 0.f, b1j = 0.f;
    if (j < HH) { w1a = w1[j]; w1b = w1[HH + j]; w1c = w1[2 * HH + j]; b1j = b1[j]; }
    for (int i = blockIdx.x; i < N; i += gridDim.x) {
        float f0 = (float)deg[i] / maxdeg;
        float f1 = (float)(dens[i] - 1) / maxdens;
        float f2 = fvar[i] / maxfv;
        if (j < HH) {
            float h = f0 * w1a + f1 * w1b + f2 * w1c + b1j;
            sh_h[j] = fmaxf(h, 0.0f);
        }
        __syncthreads();
        float acc = bj;
#pragma unroll
        for (int l = 0; l < HH; l++) acc = fmaf(sh_h[l], wv[l], acc);
        out[(size_t)i * H + j] = acc;
        __syncthreads();
    }
}

extern "C" void kernel_launch(void* const* d_in, const int* in_sizes, int n_in,
                              void* d_out, int out_size, void* d_ws, size_t ws_size,
                              hipStream_t stream) {
    const float* x      = (const float*)d_in[0];
    const int*   ei     = (const int*)d_in[1];
    const float* coords = (const float*)d_in[2];
    const float* w1     = (const float*)d_in[3];
    const float* b1     = (const float*)d_in[4];
    const float* w2     = (const float*)d_in[5];
    const float* b2     = (const float*)d_in[6];
    float* out = (float*)d_out;

    const int N = in_sizes[2] / 2;   // 16384
    const int E = in_sizes[1] / 2;   // 524288
    const int* row = ei;
    const int* col = ei + E;

    // workspace layout (int32 elements) — ~11.7MB total
    int* ws       = (int*)d_ws;
    int* deg_cnt  = ws;                          // [N]       zeroed
    int* dens_cnt = ws + N;                      // [N]       zeroed
    int* scal     = ws + 2 * N;                  // [4]       zeroed
    int* bcnt     = ws + 2 * N + 4;              // [NB2]     zeroed (reused as bfill)
    int* bptr     = bcnt + NB2;                  // [NB2+4]
    float* fvarp  = (float*)(bptr + NB2 + 4);    // [N]
    unsigned int* bedge = (unsigned int*)(fvarp + N);          // [E] u32
    unsigned short* xh  = (unsigned short*)(bedge + E);        // [N*H] fp16 (16B aligned)

    hipMemsetAsync(ws, 0, (size_t)(2 * N + 4 + NB2) * sizeof(int), stream);

    int eb = (E + 255) / 256;
    k_prep<<<eb, 256, 0, stream>>>(row, col, deg_cnt, bcnt, E);
    k_bscan<<<1, 1024, 0, stream>>>(bcnt, bptr, NB2);
    hipMemsetAsync(bcnt, 0, (size_t)NB2 * sizeof(int), stream);   // reuse as bfill
    k_bfill<<<eb, 256, 0, stream>>>(row, col, bptr, bcnt, bedge, E);

    int t4 = N * (H / 4);
    k_half<<<(t4 + 255) / 256, 256, 0, stream>>>(x, xh, t4);

    const int NSLICE = 8;
    k_density<<<dim3(N / 256, NSLICE), 256, 0, stream>>>(coords, dens_cnt, N, N / NSLICE);

    hipFuncSetAttribute((const void*)k_fvarS,
                        hipFuncAttributeMaxDynamicSharedMemorySize, 147456);
    k_fvarS<<<NWG, 512, 147456, stream>>>(x, xh, bptr, bedge, deg_cnt, dens_cnt,
                                          fvarp, scal);

    k_mlp<<<1024, 256, 0, stream>>>(w1, b1, w2, b2, deg_cnt, dens_cnt, fvarp, scal,
                                    out, N);
}